// Round 7
// baseline (128.750 us; speedup 1.0000x reference)
//
#include <hip/hip_runtime.h>

#define BB 4
#define TT 1024
#define DD 128
#define LL 16
#define CC 64   // TT/LL
#define EPSV 1e-6f

#define BTD (BB*TT*DD)
#define BCD (BB*CC*DD)

// workspace offsets (floats)
#define OFF_QC   0                  // relu(q) -> qc (in-place per slice)
#define OFF_KH   (OFF_QC + BTD)     // relu(k) -> kh
#define OFF_V    (OFF_KH + BTD)
#define OFF_G    (OFF_V  + BTD)     // sigmoid(a)
#define OFF_CL   (OFF_G  + BTD)
#define OFF_KS   (OFF_CL + BCD)
#define OFF_Z0   (OFF_KS + BCD)
#define OFF_KBT  (OFF_Z0 + BCD)     // kb transposed [B][D][T]
#define OFF_S0   (OFF_KBT + BTD)    // [B][C][D][D]

// ---------------------------------------------------------------------------
// Kernel 1 (R6-identical, proven): fused 4-projection GEMM.
// 1024 blocks (128 row-tiles x 8 mat-halves), 50KB LDS -> 3 blocks/CU.
// ---------------------------------------------------------------------------
__global__ __launch_bounds__(256) void k_gemm(
    const float* __restrict__ x,
    const float* __restrict__ Wq, const float* __restrict__ bq,
    const float* __restrict__ Wk, const float* __restrict__ bk,
    const float* __restrict__ Wv, const float* __restrict__ bv,
    const float* __restrict__ Wa, const float* __restrict__ ba,
    float* __restrict__ ws)
{
    __shared__ float xs [32][DD];
    __shared__ float wsh[64][132];

    const int tid = threadIdx.x;
    const int bx  = blockIdx.x;
    const int rt  = bx >> 3;
    const int mt  = bx & 7;
    const int m   = mt >> 1;
    const int jh  = mt & 1;

    const float* W    = (m==0)?Wq : (m==1)?Wk : (m==2)?Wv : Wa;
    const float* bias = (m==0)?bq : (m==1)?bk : (m==2)?bv : ba;

    {
        const float4* xg = (const float4*)(x + (size_t)rt*32*DD);
        #pragma unroll
        for (int r=0;r<4;r++){
            int f = tid + r*256;
            *(float4*)&xs[f>>5][(f&31)*4] = xg[f];
        }
        const float4* wg = (const float4*)(W + (size_t)jh*64*DD);
        #pragma unroll
        for (int r=0;r<8;r++){
            int f = tid + r*256;
            *(float4*)&wsh[f>>5][(f&31)*4] = wg[f];
        }
    }
    __syncthreads();

    const int ci = tid & 15;
    const int ri = tid >> 4;

    float acc[2][4];
    #pragma unroll
    for (int cc=0;cc<4;cc++){
        float bv_ = bias[jh*64 + ci + 16*cc];
        acc[0][cc]=bv_; acc[1][cc]=bv_;
    }

    #pragma unroll 2
    for (int k4=0; k4<32; k4++){
        float4 xa = *(const float4*)&xs[ri   ][k4*4];
        float4 xb = *(const float4*)&xs[ri+16][k4*4];
        #pragma unroll
        for (int cc=0;cc<4;cc++){
            float4 w = *(const float4*)&wsh[ci+16*cc][k4*4];
            acc[0][cc] = fmaf(xa.x,w.x, fmaf(xa.y,w.y, fmaf(xa.z,w.z, fmaf(xa.w,w.w, acc[0][cc]))));
            acc[1][cc] = fmaf(xb.x,w.x, fmaf(xb.y,w.y, fmaf(xb.z,w.z, fmaf(xb.w,w.w, acc[1][cc]))));
        }
    }

    float* dst = ws + ((m==0)?OFF_QC : (m==1)?OFF_KH : (m==2)?OFF_V : OFF_G);
    #pragma unroll
    for (int rr=0;rr<2;rr++){
        int row = rt*32 + ri + 16*rr;
        #pragma unroll
        for (int cc=0;cc<4;cc++){
            float v = acc[rr][cc];
            if (m==0 || m==1) v = fmaxf(v, 0.f);
            else if (m==3)    v = 1.f/(1.f+__expf(-v));
            dst[(size_t)row*DD + jh*64 + ci + 16*cc] = v;
        }
    }
}

// ---------------------------------------------------------------------------
// Kernel 2: per (chunk, col-half) postprocess — fully slice-local, no U GEMM.
// 512 blocks x 256 thr, 16KB LDS. cumprod c per column; writes qc, kh, cL,
// Ksum, and kbT[b][i][t] (transposed kb for the scan).
// ---------------------------------------------------------------------------
__global__ __launch_bounds__(256) void k_chunk(float* __restrict__ ws)
{
    __shared__ float qs [LL][64];
    __shared__ float krs[LL][64];
    __shared__ float gs [LL][64];   // sigmoid(a) -> in-place cumprod c
    __shared__ float kbs[LL][64];

    const int tid = threadIdx.x;
    const int bh  = blockIdx.x;        // bc*2 + jh
    const int bc  = bh >> 1;
    const int jh  = bh & 1;
    const int jbase = jh*64;
    const int b   = bc / CC;
    const int t0  = (bc % CC) * LL;
    const size_t tile = (size_t)(b*TT + t0)*DD;

    {   // stage own 16x64 slices of qr, kr, g (coalesced f4)
        const int t = tid >> 4, c4 = (tid & 15)*4;
        const size_t off = tile + (size_t)t*DD + jbase + c4;
        *(float4*)&qs [t][c4] = *(const float4*)(ws + OFF_QC + off);
        *(float4*)&krs[t][c4] = *(const float4*)(ws + OFF_KH + off);
        *(float4*)&gs [t][c4] = *(const float4*)(ws + OFF_G  + off);
    }
    __syncthreads();

    if (tid < 64){                     // per-column cumprod; write cL
        float c = 1.f;
        #pragma unroll
        for (int t=0;t<LL;t++){ c *= gs[t][tid]; gs[t][tid] = c; }
        ws[OFF_CL + (size_t)bc*DD + jbase + tid] = c;
    }
    __syncthreads();

    {   // qc, kh, kb (4 t-rows per thread, coalesced 64-wide stores)
        const int col = tid & 63;
        const int tg  = tid >> 6;
        const float cl = gs[LL-1][col];
        #pragma unroll
        for (int r=0;r<4;r++){
            int t = tg*4 + r;
            float cv = gs[t][col];
            ws[OFF_QC + tile + (size_t)t*DD + jbase + col] = qs[t][col] * cv;
            float kh = krs[t][col] / cv;
            ws[OFF_KH + tile + (size_t)t*DD + jbase + col] = kh;
            kbs[t][col] = kh * cl;
        }
    }
    __syncthreads();

    if (tid < 64){                     // Ksum per column
        float s = 0.f;
        #pragma unroll
        for (int t=0;t<LL;t++) s += kbs[t][tid];
        ws[OFF_KS + (size_t)bc*DD + jbase + tid] = s;
    }
    {   // kbT[b][i][t]: LDS-transposed f4 writes (64B-aligned full segments)
        const int il = tid >> 2;       // 0..63 local i
        const int tg = tid & 3;        // 4 t's
        float4 v;
        v.x = kbs[tg*4+0][il];
        v.y = kbs[tg*4+1][il];
        v.z = kbs[tg*4+2][il];
        v.w = kbs[tg*4+3][il];
        *(float4*)(ws + OFF_KBT + ((size_t)(b*DD + jbase + il)*TT + t0 + tg*4)) = v;
    }
}

// ---------------------------------------------------------------------------
// Kernel 3: per-element scan over chunks with ON-THE-FLY U:
//   U_e(ch) = sum_u kbT[i][ch*16+u] * V[ch*16+u][j]   (16 fma, LDS broadcast
//   x coalesced L2-resident v-row loads), s = fma(cL, s, U_e).
// 512 blocks (b,i) x 128 thr j; 2-chunk software pipeline for v loads.
// ---------------------------------------------------------------------------
__global__ __launch_bounds__(128) void k_scan(float* __restrict__ ws)
{
    __shared__ float kbt[TT];
    __shared__ float cls[CC], kss[CC];

    const int bi = blockIdx.x;      // b*DD + i
    const int b  = bi >> 7;
    const int i  = bi & 127;
    const int j  = threadIdx.x;

    {   // stage kb column (contiguous 4KB) + cL/Ks columns
        const float4* src = (const float4*)(ws + OFF_KBT + (size_t)(b*DD + i)*TT);
        ((float4*)kbt)[j]     = src[j];
        ((float4*)kbt)[j+128] = src[j+128];
        if (j < CC) cls[j]    = ws[OFF_CL + (size_t)(b*CC + j)*DD + i];
        else        kss[j-CC] = ws[OFF_KS + (size_t)(b*CC + j-CC)*DD + i];
    }
    __syncthreads();

    const float* Vg = ws + OFF_V + (size_t)b*TT*DD + j;
    float* s0 = ws + OFF_S0 + (size_t)b*CC*DD*DD + (size_t)i*DD + j;
    float* z0 = ws + OFF_Z0;

    float s = 0.f, z = 0.f;
    float vA[16], vB[16];

#define LOADV(dst, ch) { \
        _Pragma("unroll") \
        for (int u=0;u<16;u++) dst[u] = Vg[(size_t)((ch)*LL+u)*DD]; }

#define STEP(vv, ch) { \
        float p0 = kbt[(ch)*16+ 0]*vv[ 0] + kbt[(ch)*16+ 4]*vv[ 4] \
                 + kbt[(ch)*16+ 8]*vv[ 8] + kbt[(ch)*16+12]*vv[12]; \
        float p1 = kbt[(ch)*16+ 1]*vv[ 1] + kbt[(ch)*16+ 5]*vv[ 5] \
                 + kbt[(ch)*16+ 9]*vv[ 9] + kbt[(ch)*16+13]*vv[13]; \
        float p2 = kbt[(ch)*16+ 2]*vv[ 2] + kbt[(ch)*16+ 6]*vv[ 6] \
                 + kbt[(ch)*16+10]*vv[10] + kbt[(ch)*16+14]*vv[14]; \
        float p3 = kbt[(ch)*16+ 3]*vv[ 3] + kbt[(ch)*16+ 7]*vv[ 7] \
                 + kbt[(ch)*16+11]*vv[11] + kbt[(ch)*16+15]*vv[15]; \
        float Ue = (p0+p1)+(p2+p3); \
        s0[(size_t)(ch)*DD*DD] = s; \
        if (j==0) z0[(size_t)(b*CC+(ch))*DD + i] = z; \
        s = fmaf(cls[ch], s, Ue); \
        z = fmaf(cls[ch], z, kss[ch]); }

    LOADV(vA, 0);
    for (int ch=0; ch<CC; ch+=2){
        LOADV(vB, ch+1);
        STEP(vA, ch);
        if (ch+2 < CC) LOADV(vA, ch+2);
        STEP(vB, ch+1);
    }
#undef LOADV
#undef STEP
}

// ---------------------------------------------------------------------------
// Kernel 4 (R6-identical, proven): per (chunk, j-half) output.
// ---------------------------------------------------------------------------
__global__ __launch_bounds__(256) void k_out(const float* __restrict__ ws, float* __restrict__ y)
{
    __shared__ float qcs[LL][DD+4];
    __shared__ float khs[LL][DD+4];
    __shared__ float vsm[LL][64+4];
    __shared__ float Ss[LL][LL];
    __shared__ float denS[LL];
    __shared__ float z0s[DD];
    __shared__ float s0s[2][32][64+4];

    const int tid = threadIdx.x;
    const int bh  = blockIdx.x;        // bc*2 + jh
    const int bc  = bh >> 1;
    const int jh  = bh & 1;
    const int jbase = jh * 64;
    const int b   = bc / CC;
    const int ch  = bc % CC;
    const int t0  = ch * LL;
    const size_t tile = (size_t)(b*TT + t0)*DD;
    const float* s0g = ws + OFF_S0 + (size_t)bc*DD*DD;

    float4 pre[2];
    {
        const float4* qcg = (const float4*)(ws + OFF_QC + tile);
        const float4* khg = (const float4*)(ws + OFF_KH + tile);
        #pragma unroll
        for (int rep=0; rep<2; rep++){
            int f = tid + rep*256;
            int t = f >> 5, k4 = f & 31;
            *(float4*)&qcs[t][k4*4] = qcg[f];
            *(float4*)&khs[t][k4*4] = khg[f];
        }
        {
            int t = tid >> 4, c = (tid & 15)*4;
            *(float4*)&vsm[t][c] =
                *(const float4*)(ws + OFF_V + tile + (size_t)t*DD + jbase + c);
        }
        if (tid < DD) z0s[tid] = ws[OFF_Z0 + (size_t)bc*DD + tid];
        #pragma unroll
        for (int r=0;r<2;r++){
            int f = tid + r*256;
            int row = f >> 4, c4 = (f & 15)*4;
            pre[r] = *(const float4*)(s0g + (size_t)row*DD + jbase + c4);
        }
    }
    __syncthreads();

    {
        int t = tid >> 4, u = tid & 15;
        float s = 0.f;
        #pragma unroll 8
        for (int k4=0; k4<32; k4++){
            float4 q4 = *(const float4*)&qcs[t][k4*4];
            float4 h4 = *(const float4*)&khs[u][k4*4];
            s = fmaf(q4.x,h4.x, fmaf(q4.y,h4.y, fmaf(q4.z,h4.z, fmaf(q4.w,h4.w, s))));
        }
        Ss[t][u] = (u <= t) ? s : 0.f;
    }
    __syncthreads();

    if (tid < LL){
        int t = tid;
        float d = EPSV;
        for (int u=0; u<=t; u++) d += Ss[t][u];
        #pragma unroll 8
        for (int kk=0; kk<DD; kk++) d += qcs[t][kk]*z0s[kk];
        denS[t] = d;
    }

    const int t  = tid >> 4;
    const int jg = tid & 15;
    const int j0 = jg * 4;
    float y4[4] = {0.f,0.f,0.f,0.f};

    __syncthreads();
    #pragma unroll
    for (int u=0; u<LL; u++){
        float sv = Ss[t][u];
        float4 v4 = *(const float4*)&vsm[u][j0];
        y4[0]=fmaf(sv,v4.x,y4[0]); y4[1]=fmaf(sv,v4.y,y4[1]);
        y4[2]=fmaf(sv,v4.z,y4[2]); y4[3]=fmaf(sv,v4.w,y4[3]);
    }

    #pragma unroll
    for (int sl=0; sl<4; sl++){
        __syncthreads();
        #pragma unroll
        for (int r=0;r<2;r++){
            int f = tid + r*256;
            *(float4*)&s0s[sl&1][f>>4][(f&15)*4] = pre[r];
        }
        if (sl < 3){
            #pragma unroll
            for (int r=0;r<2;r++){
                int f = tid + r*256;
                int row = f >> 4, c4 = (f & 15)*4;
                pre[r] = *(const float4*)(s0g + (size_t)((sl+1)*32 + row)*DD + jbase + c4);
            }
        }
        __syncthreads();
        #pragma unroll 8
        for (int ii=0; ii<32; ii++){
            float qv = qcs[t][sl*32+ii];
            float4 s4 = *(const float4*)&s0s[sl&1][ii][j0];
            y4[0]=fmaf(qv,s4.x,y4[0]); y4[1]=fmaf(qv,s4.y,y4[1]);
            y4[2]=fmaf(qv,s4.z,y4[2]); y4[3]=fmaf(qv,s4.w,y4[3]);
        }
    }

    const float rd = 1.f/denS[t];
    float* yg = y + tile + (size_t)t*DD + jbase + j0;
    *(float4*)yg = make_float4(y4[0]*rd, y4[1]*rd, y4[2]*rd, y4[3]*rd);
}

extern "C" void kernel_launch(void* const* d_in, const int* in_sizes, int n_in,
                              void* d_out, int out_size, void* d_ws, size_t ws_size,
                              hipStream_t stream)
{
    const float* x  = (const float*)d_in[0];
    const float* Wq = (const float*)d_in[1]; const float* bq = (const float*)d_in[2];
    const float* Wk = (const float*)d_in[3]; const float* bk = (const float*)d_in[4];
    const float* Wv = (const float*)d_in[5]; const float* bv = (const float*)d_in[6];
    const float* Wa = (const float*)d_in[7]; const float* ba = (const float*)d_in[8];
    float* ws = (float*)d_ws;
    float* yo = (float*)d_out;

    hipLaunchKernelGGL(k_gemm,  dim3(1024),    dim3(256), 0, stream,
                       x, Wq,bq, Wk,bk, Wv,bv, Wa,ba, ws);
    hipLaunchKernelGGL(k_chunk, dim3(BB*CC*2), dim3(256), 0, stream, ws);
    hipLaunchKernelGGL(k_scan,  dim3(BB*DD),   dim3(128), 0, stream, ws);
    hipLaunchKernelGGL(k_out,   dim3(BB*CC*2), dim3(256), 0, stream, ws, yo);
}

// Round 8
// 115.223 us; speedup vs baseline: 1.1174x; 1.1174x over previous
//
#include <hip/hip_runtime.h>

#define BB 4
#define TT 1024
#define DD 128
#define LL 16
#define CC 64   // TT/LL
#define EPSV 1e-6f

#define BTD (BB*TT*DD)
#define BCD (BB*CC*DD)

// workspace offsets (floats)
#define OFF_QC   0                  // relu(q) -> qc (in-place)
#define OFF_KH   (OFF_QC + BTD)     // relu(k) -> kh (in-place)
#define OFF_V    (OFF_KH + BTD)
#define OFF_G    (OFF_V  + BTD)     // sigmoid(a)
#define OFF_CL   (OFF_G  + BTD)
#define OFF_KS   (OFF_CL + BCD)
#define OFF_Z0   (OFF_KS + BCD)
#define OFF_U    (OFF_Z0 + BCD)     // [B][C][D][D]
#define OFF_S0   (OFF_U  + BB*CC*DD*DD)

// ---------------------------------------------------------------------------
// Kernel 1 (proven): fused 4-projection GEMM.
// 1024 blocks (128 row-tiles x 8 mat-halves), 50KB LDS -> 3 blocks/CU.
// ---------------------------------------------------------------------------
__global__ __launch_bounds__(256) void k_gemm(
    const float* __restrict__ x,
    const float* __restrict__ Wq, const float* __restrict__ bq,
    const float* __restrict__ Wk, const float* __restrict__ bk,
    const float* __restrict__ Wv, const float* __restrict__ bv,
    const float* __restrict__ Wa, const float* __restrict__ ba,
    float* __restrict__ ws)
{
    __shared__ float xs [32][DD];
    __shared__ float wsh[64][132];

    const int tid = threadIdx.x;
    const int bx  = blockIdx.x;
    const int rt  = bx >> 3;
    const int mt  = bx & 7;
    const int m   = mt >> 1;
    const int jh  = mt & 1;

    const float* W    = (m==0)?Wq : (m==1)?Wk : (m==2)?Wv : Wa;
    const float* bias = (m==0)?bq : (m==1)?bk : (m==2)?bv : ba;

    {
        const float4* xg = (const float4*)(x + (size_t)rt*32*DD);
        #pragma unroll
        for (int r=0;r<4;r++){
            int f = tid + r*256;
            *(float4*)&xs[f>>5][(f&31)*4] = xg[f];
        }
        const float4* wg = (const float4*)(W + (size_t)jh*64*DD);
        #pragma unroll
        for (int r=0;r<8;r++){
            int f = tid + r*256;
            *(float4*)&wsh[f>>5][(f&31)*4] = wg[f];
        }
    }
    __syncthreads();

    const int ci = tid & 15;
    const int ri = tid >> 4;

    float acc[2][4];
    #pragma unroll
    for (int cc=0;cc<4;cc++){
        float bv_ = bias[jh*64 + ci + 16*cc];
        acc[0][cc]=bv_; acc[1][cc]=bv_;
    }

    #pragma unroll 2
    for (int k4=0; k4<32; k4++){
        float4 xa = *(const float4*)&xs[ri   ][k4*4];
        float4 xb = *(const float4*)&xs[ri+16][k4*4];
        #pragma unroll
        for (int cc=0;cc<4;cc++){
            float4 w = *(const float4*)&wsh[ci+16*cc][k4*4];
            acc[0][cc] = fmaf(xa.x,w.x, fmaf(xa.y,w.y, fmaf(xa.z,w.z, fmaf(xa.w,w.w, acc[0][cc]))));
            acc[1][cc] = fmaf(xb.x,w.x, fmaf(xb.y,w.y, fmaf(xb.z,w.z, fmaf(xb.w,w.w, acc[1][cc]))));
        }
    }

    float* dst = ws + ((m==0)?OFF_QC : (m==1)?OFF_KH : (m==2)?OFF_V : OFF_G);
    #pragma unroll
    for (int rr=0;rr<2;rr++){
        int row = rt*32 + ri + 16*rr;
        #pragma unroll
        for (int cc=0;cc<4;cc++){
            float v = acc[rr][cc];
            if (m==0 || m==1) v = fmaxf(v, 0.f);
            else if (m==3)    v = 1.f/(1.f+__expf(-v));
            dst[(size_t)row*DD + jh*64 + ci + 16*cc] = v;
        }
    }
}

// ---------------------------------------------------------------------------
// Kernel 2: per (chunk, half) postprocess + U half-GEMM, no redundancy.
// Block owns cols/rows [64h, 64h+64): cumprod, qc, kh, kb, cL, Ksum for own
// cols; U rows own half x all j (needs v full width). 512 blocks x 256 thr,
// 24KB LDS -> 6 blocks/CU.
// ---------------------------------------------------------------------------
__global__ __launch_bounds__(256) void k_chunk(float* __restrict__ ws)
{
    __shared__ float qs [LL][64];
    __shared__ float krs[LL][64];
    __shared__ float gs [LL][64];   // sigmoid(a) -> in-place cumprod c
    __shared__ float vs [LL][DD];
    __shared__ float kbs[LL][64];

    const int tid = threadIdx.x;
    const int bh  = blockIdx.x;        // bc*2 + h
    const int bc  = bh >> 1;
    const int h   = bh & 1;
    const int ibase = h*64;
    const int b   = bc / CC;
    const int t0  = (bc % CC) * LL;
    const size_t tile = (size_t)(b*TT + t0)*DD;

    {   // stage own 16x64 slices of q,k,g + v full 16x128
        const int t = tid >> 4, c4 = (tid & 15)*4;
        const size_t off = tile + (size_t)t*DD + ibase + c4;
        *(float4*)&qs [t][c4] = *(const float4*)(ws + OFF_QC + off);
        *(float4*)&krs[t][c4] = *(const float4*)(ws + OFF_KH + off);
        *(float4*)&gs [t][c4] = *(const float4*)(ws + OFF_G  + off);
        const int tv = tid >> 5, cv = (tid & 31)*4;
        *(float4*)&vs[tv  ][cv] = *(const float4*)(ws + OFF_V + tile + (size_t)tv*DD + cv);
        *(float4*)&vs[tv+8][cv] = *(const float4*)(ws + OFF_V + tile + (size_t)(tv+8)*DD + cv);
    }
    __syncthreads();

    if (tid < 64){                     // per-column cumprod; write cL
        float c = 1.f;
        #pragma unroll
        for (int t=0;t<LL;t++){ c *= gs[t][tid]; gs[t][tid] = c; }
        ws[OFF_CL + (size_t)bc*DD + ibase + tid] = c;
    }
    __syncthreads();

    {   // qc, kh, kb (4 t-rows per thread, coalesced 64-wide stores)
        const int col = tid & 63;
        const int tg  = tid >> 6;
        const float cl = gs[LL-1][col];
        #pragma unroll
        for (int r=0;r<4;r++){
            int t = tg*4 + r;
            float cv = gs[t][col];
            ws[OFF_QC + tile + (size_t)t*DD + ibase + col] = qs[t][col] * cv;
            float kh = krs[t][col] / cv;
            ws[OFF_KH + tile + (size_t)t*DD + ibase + col] = kh;
            kbs[t][col] = kh * cl;
        }
    }
    __syncthreads();

    if (tid < 64){                     // Ksum per own column
        float s = 0.f;
        #pragma unroll
        for (int t=0;t<LL;t++) s += kbs[t][tid];
        ws[OFF_KS + (size_t)bc*DD + ibase + tid] = s;
    }

    // U[ibase+il][j] = sum_u kb[u][il]*v[u][j]; thread=(j=tid&127, ih=tid>>7)
    const int j  = tid & 127;
    const int ih = tid >> 7;           // 0/1 -> 32 rows each
    float vr[LL];
    #pragma unroll
    for (int u=0;u<LL;u++) vr[u]=vs[u][j];
    float* Ug = ws + OFF_U + (size_t)bc*DD*DD;
    #pragma unroll
    for (int i4=0;i4<8;i4++){
        int il = ih*32 + i4*4;
        float a0=0.f,a1=0.f,a2=0.f,a3=0.f;
        #pragma unroll
        for (int u=0;u<LL;u++){
            float4 kb4 = *(const float4*)(&kbs[u][il]);   // wave-broadcast
            float vu = vr[u];
            a0 = fmaf(kb4.x,vu,a0); a1 = fmaf(kb4.y,vu,a1);
            a2 = fmaf(kb4.z,vu,a2); a3 = fmaf(kb4.w,vu,a3);
        }
        Ug[(size_t)(ibase+il+0)*DD + j]=a0; Ug[(size_t)(ibase+il+1)*DD + j]=a1;
        Ug[(size_t)(ibase+il+2)*DD + j]=a2; Ug[(size_t)(ibase+il+3)*DD + j]=a3;
    }
}

// ---------------------------------------------------------------------------
// Kernel 3 (R6-proven): per-element scan over chunks, 16-deep prefetch ring.
// 512 blocks x 128 threads.
// ---------------------------------------------------------------------------
__global__ __launch_bounds__(128) void k_scan(float* __restrict__ ws)
{
    __shared__ float cls[CC], kss[CC];
    const int bi = blockIdx.x;      // b*DD + i
    const int b  = bi >> 7;
    const int i  = bi & 127;
    const int j  = threadIdx.x;

    if (j < CC) cls[j]      = ws[OFF_CL + (size_t)(b*CC + j)*DD + i];
    else        kss[j - CC] = ws[OFF_KS + (size_t)(b*CC + j - CC)*DD + i];
    __syncthreads();

    const float* U  = ws + OFF_U;
    float*       s0 = ws + OFF_S0;
    float*       z0 = ws + OFF_Z0;
    const size_t base = (size_t)b*CC*DD*DD + (size_t)i*DD + j;

    float up[16];
    #pragma unroll
    for (int p=0;p<16;p++) up[p] = U[base + (size_t)p*DD*DD];

    float s = 0.f, z = 0.f;
    #pragma unroll
    for (int ch=0; ch<CC; ch++){
        s0[base + (size_t)ch*DD*DD] = s;
        if (j==0) z0[(size_t)(b*CC+ch)*DD + i] = z;
        float u  = up[ch & 15];
        if (ch + 16 < CC) up[ch & 15] = U[base + (size_t)(ch+16)*DD*DD];
        float cl = cls[ch];
        s = fmaf(cl, s, u);
        z = fmaf(cl, z, kss[ch]);
    }
}

// ---------------------------------------------------------------------------
// Kernel 4 (proven): per (chunk, j-half) output.
// ---------------------------------------------------------------------------
__global__ __launch_bounds__(256) void k_out(const float* __restrict__ ws, float* __restrict__ y)
{
    __shared__ float qcs[LL][DD+4];
    __shared__ float khs[LL][DD+4];
    __shared__ float vsm[LL][64+4];
    __shared__ float Ss[LL][LL];
    __shared__ float denS[LL];
    __shared__ float z0s[DD];
    __shared__ float s0s[2][32][64+4];

    const int tid = threadIdx.x;
    const int bh  = blockIdx.x;        // bc*2 + jh
    const int bc  = bh >> 1;
    const int jh  = bh & 1;
    const int jbase = jh * 64;
    const int b   = bc / CC;
    const int ch  = bc % CC;
    const int t0  = ch * LL;
    const size_t tile = (size_t)(b*TT + t0)*DD;
    const float* s0g = ws + OFF_S0 + (size_t)bc*DD*DD;

    float4 pre[2];
    {
        const float4* qcg = (const float4*)(ws + OFF_QC + tile);
        const float4* khg = (const float4*)(ws + OFF_KH + tile);
        #pragma unroll
        for (int rep=0; rep<2; rep++){
            int f = tid + rep*256;
            int t = f >> 5, k4 = f & 31;
            *(float4*)&qcs[t][k4*4] = qcg[f];
            *(float4*)&khs[t][k4*4] = khg[f];
        }
        {
            int t = tid >> 4, c = (tid & 15)*4;
            *(float4*)&vsm[t][c] =
                *(const float4*)(ws + OFF_V + tile + (size_t)t*DD + jbase + c);
        }
        if (tid < DD) z0s[tid] = ws[OFF_Z0 + (size_t)bc*DD + tid];
        #pragma unroll
        for (int r=0;r<2;r++){
            int f = tid + r*256;
            int row = f >> 4, c4 = (f & 15)*4;
            pre[r] = *(const float4*)(s0g + (size_t)row*DD + jbase + c4);
        }
    }
    __syncthreads();

    {
        int t = tid >> 4, u = tid & 15;
        float s = 0.f;
        #pragma unroll 8
        for (int k4=0; k4<32; k4++){
            float4 q4 = *(const float4*)&qcs[t][k4*4];
            float4 h4 = *(const float4*)&khs[u][k4*4];
            s = fmaf(q4.x,h4.x, fmaf(q4.y,h4.y, fmaf(q4.z,h4.z, fmaf(q4.w,h4.w, s))));
        }
        Ss[t][u] = (u <= t) ? s : 0.f;
    }
    __syncthreads();

    if (tid < LL){
        int t = tid;
        float d = EPSV;
        for (int u=0; u<=t; u++) d += Ss[t][u];
        #pragma unroll 8
        for (int kk=0; kk<DD; kk++) d += qcs[t][kk]*z0s[kk];
        denS[t] = d;
    }

    const int t  = tid >> 4;
    const int jg = tid & 15;
    const int j0 = jg * 4;
    float y4[4] = {0.f,0.f,0.f,0.f};

    __syncthreads();
    #pragma unroll
    for (int u=0; u<LL; u++){
        float sv = Ss[t][u];
        float4 v4 = *(const float4*)&vsm[u][j0];
        y4[0]=fmaf(sv,v4.x,y4[0]); y4[1]=fmaf(sv,v4.y,y4[1]);
        y4[2]=fmaf(sv,v4.z,y4[2]); y4[3]=fmaf(sv,v4.w,y4[3]);
    }

    #pragma unroll
    for (int sl=0; sl<4; sl++){
        __syncthreads();
        #pragma unroll
        for (int r=0;r<2;r++){
            int f = tid + r*256;
            *(float4*)&s0s[sl&1][f>>4][(f&15)*4] = pre[r];
        }
        if (sl < 3){
            #pragma unroll
            for (int r=0;r<2;r++){
                int f = tid + r*256;
                int row = f >> 4, c4 = (f & 15)*4;
                pre[r] = *(const float4*)(s0g + (size_t)((sl+1)*32 + row)*DD + jbase + c4);
            }
        }
        __syncthreads();
        #pragma unroll 8
        for (int ii=0; ii<32; ii++){
            float qv = qcs[t][sl*32+ii];
            float4 s4 = *(const float4*)&s0s[sl&1][ii][j0];
            y4[0]=fmaf(qv,s4.x,y4[0]); y4[1]=fmaf(qv,s4.y,y4[1]);
            y4[2]=fmaf(qv,s4.z,y4[2]); y4[3]=fmaf(qv,s4.w,y4[3]);
        }
    }

    const float rd = 1.f/denS[t];
    float* yg = y + tile + (size_t)t*DD + jbase + j0;
    *(float4*)yg = make_float4(y4[0]*rd, y4[1]*rd, y4[2]*rd, y4[3]*rd);
}

extern "C" void kernel_launch(void* const* d_in, const int* in_sizes, int n_in,
                              void* d_out, int out_size, void* d_ws, size_t ws_size,
                              hipStream_t stream)
{
    const float* x  = (const float*)d_in[0];
    const float* Wq = (const float*)d_in[1]; const float* bq = (const float*)d_in[2];
    const float* Wk = (const float*)d_in[3]; const float* bk = (const float*)d_in[4];
    const float* Wv = (const float*)d_in[5]; const float* bv = (const float*)d_in[6];
    const float* Wa = (const float*)d_in[7]; const float* ba = (const float*)d_in[8];
    float* ws = (float*)d_ws;
    float* yo = (float*)d_out;

    hipLaunchKernelGGL(k_gemm,  dim3(1024),    dim3(256), 0, stream,
                       x, Wq,bq, Wk,bk, Wv,bv, Wa,ba, ws);
    hipLaunchKernelGGL(k_chunk, dim3(BB*CC*2), dim3(256), 0, stream, ws);
    hipLaunchKernelGGL(k_scan,  dim3(BB*DD),   dim3(128), 0, stream, ws);
    hipLaunchKernelGGL(k_out,   dim3(BB*CC*2), dim3(256), 0, stream, ws, yo);
}